// Round 18
// baseline (242.771 us; speedup 1.0000x reference)
//
#include <hip/hip_runtime.h>

typedef unsigned int uint;
typedef unsigned short ushort;

#define TT 16384      // tokens = B*S
#define DD 1024       // d_model
#define EE 32         // experts
#define ESS 128       // expert size
#define VV 1024       // v dim
#define KK 4          // top-k
#define TILE 64
#define NTILE_MAX 1056   // 16384*4/64 + 32 ; == 8*132 (XCD-swizzle friendly)
#define RSPLIT 8         // router D-split

typedef __attribute__((ext_vector_type(8))) short bf16x8;   // 8 bf16 = 4 VGPR
typedef __attribute__((ext_vector_type(16))) float f32x16;

// ---------------- ws layout (offsets in 4B units) ----------------
#define WS_SELRAW   0                       // 524288 f (unused, layout stability)
#define WS_GATES    524288                  // 65536 f
#define WS_PGATE    589824                  // 65536 f
#define WS_STATS    655360                  // lm_sums 32 f + counts 32 i (zeroed by k_router blk0)
#define WS_LMSUMS   655360
#define WS_COUNTS   655392
#define WS_OFFSETS  655424                  // 33 i
#define WS_CURSORS  655457                  // 32 i
#define WS_NTILES   655489                  // 1 i
#define WS_TMAPE    655490                  // 1056 i
#define WS_TMAPT    656546                  // 1056 i
#define WS_IDXS     657602                  // 65536 i
#define WS_PERM     723138                  // 65536 i
// bf16 buffers (16B-aligned starts, sizes in uint units)
#define WS_XB       788736                  // x bf16 [16384][1024] -> 8388608 uints
#define WS_KF       9177344                 // keys frag-major [32][64][4][64][8] -> 2097152 uints
#define WS_VF       11274496                // values frag-major [32][32][8][64][8] -> 2097152 uints
#define WS_ISLOT    13371648                // token -> 4 slot ids, 65536 i
#define WS_STG      13437184                // slot partials bf16 [65536][1024] -> 33554432 uints
#define WS_NEED_U   46991616ull             // uints needed for staging path
// router partials [RSPLIT][TT][EE] f32 alias onto WS_STG (written later by
// k_expert) or, in the fallback, onto WS_KF..WS_VF (written later by k_prep,
// which therefore launches AFTER k_token).

// fp32 -> bf16 RNE
__device__ __forceinline__ ushort f2b(float f) {
    uint u = __builtin_bit_cast(uint, f);
    u = (u + 0x7fffu + ((u >> 16) & 1u)) >> 16;
    return (ushort)u;
}
__device__ __forceinline__ uint bpack(float lo, float hi) {
    return (uint)f2b(lo) | ((uint)f2b(hi) << 16);
}
__device__ __forceinline__ float b2f(ushort b) {
    uint u = (uint)b << 16;
    return __builtin_bit_cast(float, u);
}

// async global->LDS, 16B per lane; LDS dest = wave-uniform base + lane*16,
// global src is per-lane (m104/m173 semantics)
__device__ __forceinline__ void gload_lds16(const void* g, void* l) {
    __builtin_amdgcn_global_load_lds(
        (const __attribute__((address_space(1))) uint*)g,
        (__attribute__((address_space(3))) uint*)l, 16, 0, 0);
}

// ------------- fused weight prep: keys + values -> B-fragment-major bf16 ---
__global__ __launch_bounds__(256) void k_prep(const float* __restrict__ keys,
                                              const float* __restrict__ values,
                                              ushort* __restrict__ kfb,
                                              ushort* __restrict__ vfb) {
    const int l = threadIdx.x & 63;
    int b = blockIdx.x;
    if (b < EE * 64) {
        const int e = b >> 6, ks = b & 63;
        const int nf = threadIdx.x >> 6;
        const int f = nf * 32 + (l & 31);
        const int d0 = ks * 16 + (l >> 5) * 8;
        const float* src = keys + ((size_t)e * DD + d0) * ESS + f;
        float v[8];
#pragma unroll
        for (int j = 0; j < 8; j++) v[j] = src[(size_t)j * ESS];
        uint4 r = { bpack(v[0], v[1]), bpack(v[2], v[3]), bpack(v[4], v[5]), bpack(v[6], v[7]) };
        const size_t off = (((size_t)e * 64 + ks) * 4 + nf) * 512 + l * 8;
        *(uint4*)(kfb + off) = r;
    } else {
        b -= EE * 64;
        const int half = b & 1;
        const int env = b >> 1;
        const int e = env >> 5, nv = env & 31;
        const int ks = (threadIdx.x >> 6) + half * 4;
        const int v0 = nv * 32 + (l & 31);
        const int f0 = ks * 16 + (l >> 5) * 8;
        const float* src = values + ((size_t)e * ESS + f0) * VV + v0;
        float v[8];
#pragma unroll
        for (int j = 0; j < 8; j++) v[j] = src[(size_t)j * VV];
        uint4 r = { bpack(v[0], v[1]), bpack(v[2], v[3]), bpack(v[4], v[5]), bpack(v[6], v[7]) };
        const size_t off = (((size_t)e * 32 + nv) * 8 + ks) * 512 + l * 8;
        *(uint4*)(vfb + off) = r;
    }
}

// ------------- router: sel_part[c] = X * Wsel^T over D-chunk c (fp32!) ----
// fp32 on purpose: bf16 logits flip ~1% of top-4 picks -> O(1) output errors.
// Block (0,0) zeroes the stats region (safe: k_token runs after, stream order).
// r18: 128-thread blocks, 2 experts x 8 tokens per thread. LDS-read ledger:
// r17 (2x4): 6 ds_read_b128/d4 per 32 MACs -> 1152cy LDS vs 1024cy VALU/chunk
// (still LDS-bound). (2x8): 10/d4 per 64 MACs -> per-block reads 24576->20480
// (-17%), VALU unchanged -> VALU-bound. Same d-accumulation order per output
// (bit-identical numerics), coalesced float2 writes.
__global__ __launch_bounds__(128) void k_router(const float* __restrict__ x,
                                                const float* __restrict__ sel,
                                                float* __restrict__ sel_part,
                                                uint* __restrict__ xbu,
                                                float* __restrict__ stats) {
    __shared__ float xs[64][68];
    __shared__ float ss[32][68];
    const int tid = threadIdx.x;
    if (blockIdx.x == 0 && blockIdx.y == 0 && tid < 64) stats[tid] = 0.f;
    const int t0 = blockIdx.x * 64;
    const int dch = blockIdx.y;                 // D-chunk 0..RSPLIT-1
    const int eg = tid & 15;                    // expert pair: 2eg, 2eg+1
    const int tg = tid >> 4;                    // token group: tg*8..+7
    float acc0[8], acc1[8];
#pragma unroll
    for (int i = 0; i < 8; i++) { acc0[i] = 0.f; acc1[i] = 0.f; }

    const int dlen = DD / RSPLIT;               // 128
    for (int dc = dch * dlen; dc < dch * dlen + dlen; dc += 64) {
#pragma unroll
        for (int i = 0; i < 8; i++) {            // stage x 64x64 (8 float4/thread)
            int q = tid + 128 * i;
            int r = q >> 4, c4 = q & 15;
            size_t gi = (size_t)(t0 + r) * DD + dc + c4 * 4;
            float4 v = *(const float4*)&x[gi];
            *(float4*)&xs[r][c4 * 4] = v;
            uint2 bv = { bpack(v.x, v.y), bpack(v.z, v.w) };   // fused bf16 emit
            *(uint2*)&xbu[gi / 2] = bv;
        }
#pragma unroll
        for (int i = 0; i < 4; i++) {            // stage sel 32x64 (4 float4/thread)
            int q = tid + 128 * i;
            int e = q >> 4, c4 = q & 15;
            float4 v = *(const float4*)&sel[(size_t)e * DD + dc + c4 * 4];
            *(float4*)&ss[e][c4 * 4] = v;
        }
        __syncthreads();
#pragma unroll
        for (int d4 = 0; d4 < 16; d4++) {
            float4 sv0 = *(const float4*)&ss[2 * eg][d4 * 4];
            float4 sv1 = *(const float4*)&ss[2 * eg + 1][d4 * 4];
#pragma unroll
            for (int i = 0; i < 8; i++) {
                float4 xv = *(const float4*)&xs[tg * 8 + i][d4 * 4];
                acc0[i] += xv.x * sv0.x + xv.y * sv0.y + xv.z * sv0.z + xv.w * sv0.w;
                acc1[i] += xv.x * sv1.x + xv.y * sv1.y + xv.z * sv1.z + xv.w * sv1.w;
            }
        }
        __syncthreads();
    }
    float* dst = sel_part + (size_t)dch * TT * EE;
#pragma unroll
    for (int i = 0; i < 8; i++) {
        float2 o = { acc0[i], acc1[i] };
        *(float2*)&dst[(size_t)(t0 + tg * 8 + i) * EE + 2 * eg] = o;
    }
}

// ------------- per-token: sum partials, lse, sigmoid, top-4 ---------------
__global__ __launch_bounds__(256) void k_token(const float* __restrict__ sel_part,
                                               float* __restrict__ gates,
                                               int* __restrict__ idxs,
                                               float* __restrict__ lm_sums,
                                               int* __restrict__ counts) {
    __shared__ int hist[EE];
    __shared__ float lmh[EE];
    const int tid = threadIdx.x;
    if (tid < EE) { hist[tid] = 0; lmh[tid] = 0.f; }
    __syncthreads();

    const int t = blockIdx.x * 256 + tid;
    float v[32];
#pragma unroll
    for (int j = 0; j < 8; j++) {
        float4 q[RSPLIT];
#pragma unroll
        for (int p = 0; p < RSPLIT; p++)
            q[p] = *(const float4*)&sel_part[((size_t)p * TT + t) * EE + j * 4];
        v[j * 4 + 0] = ((q[0].x + q[1].x) + (q[2].x + q[3].x)) + ((q[4].x + q[5].x) + (q[6].x + q[7].x));
        v[j * 4 + 1] = ((q[0].y + q[1].y) + (q[2].y + q[3].y)) + ((q[4].y + q[5].y) + (q[6].y + q[7].y));
        v[j * 4 + 2] = ((q[0].z + q[1].z) + (q[2].z + q[3].z)) + ((q[4].z + q[5].z) + (q[6].z + q[7].z));
        v[j * 4 + 3] = ((q[0].w + q[1].w) + (q[2].w + q[3].w)) + ((q[4].w + q[5].w) + (q[6].w + q[7].w));
    }
    float m = v[0];
#pragma unroll
    for (int e = 1; e < 32; e++) m = fmaxf(m, v[e]);
    float s = 0.f;
#pragma unroll
    for (int e = 0; e < 32; e++) s += expf(v[e] - m);
    const float lse = logf(s) + m;

    float sg[32];
#pragma unroll
    for (int e = 0; e < 32; e++) sg[e] = 1.f / (1.f + expf(-v[e]));

    unsigned taken = 0u;
#pragma unroll
    for (int k = 0; k < KK; k++) {
        float best = -1.f; int bi = 0;
#pragma unroll
        for (int e = 0; e < 32; e++) {
            bool free_e = !((taken >> e) & 1u);
            if (free_e && sg[e] > best) { best = sg[e]; bi = e; }
        }
        taken |= 1u << bi;
        gates[t * KK + k] = best;
        idxs[t * KK + k] = bi;
        atomicAdd(&hist[bi], 1);
    }

#pragma unroll
    for (int e = 0; e < 32; e++) {
        float pv = expf(v[e] - lse);
#pragma unroll
        for (int o = 32; o >= 1; o >>= 1) pv += __shfl_xor(pv, o, 64);
        if ((tid & 63) == 0) atomicAdd(&lmh[e], pv);
    }
    __syncthreads();
    if (tid < EE) {
        atomicAdd(&counts[tid], hist[tid]);
        atomicAdd(&lm_sums[tid], lmh[tid]);
    }
}

// ------------- wave-parallel: scan counts, tile map, reg_loss -------------
__global__ void k_scan(const int* __restrict__ counts, int* __restrict__ offsets,
                       int* __restrict__ cursors, int* __restrict__ tmape,
                       int* __restrict__ tmapt, int* __restrict__ ntiles,
                       const float* __restrict__ lm_sums, float* __restrict__ out_reg) {
    const int lane = threadIdx.x;          // one wave of 64
    int c = (lane < EE) ? counts[lane] : 0;
    int p = c;
#pragma unroll
    for (int o = 1; o < 32; o <<= 1) { int u = __shfl_up(p, o, 64); if (lane >= o) p += u; }
    const int off = p - c;
    if (lane < EE) { offsets[lane] = off; cursors[lane] = off; }
    if (lane == EE - 1) offsets[EE] = p;

    int nt = (c + TILE - 1) / TILE;
    int q = nt;
#pragma unroll
    for (int o = 1; o < 32; o <<= 1) { int u = __shfl_up(q, o, 64); if (lane >= o) q += u; }
    const int tb = q - nt;
    if (lane < EE)
        for (int j = 0; j < nt; j++) { tmape[tb + j] = lane; tmapt[tb + j] = j; }
    if (lane == EE - 1) ntiles[0] = q;

    float rv = 0.f;
    if (lane < EE) {
        float pe = lm_sums[lane] * (1.f / (float)TT);
        rv = pe * logf(pe);
    }
#pragma unroll
    for (int o = 16; o >= 1; o >>= 1) rv += __shfl_down(rv, o, 64);
    if (lane == 0) out_reg[0] = rv;
}

// ------------- scatter token ids into per-expert buckets (block-agg) ------
__global__ __launch_bounds__(256) void k_scatter(const int* __restrict__ idxs,
                                                 const float* __restrict__ gates,
                                                 int* __restrict__ cursors,
                                                 int* __restrict__ perm,
                                                 float* __restrict__ pgate,
                                                 int* __restrict__ islot) {
    __shared__ int lh[EE];
    __shared__ int lbase[EE];
    const int tid = threadIdx.x;
    if (tid < EE) lh[tid] = 0;
    __syncthreads();
    const int t = blockIdx.x * 256 + tid;
    int ee[KK], rk[KK];
#pragma unroll
    for (int k = 0; k < KK; k++) {
        ee[k] = idxs[t * KK + k];
        rk[k] = atomicAdd(&lh[ee[k]], 1);
    }
    __syncthreads();
    if (tid < EE) lbase[tid] = atomicAdd(&cursors[tid], lh[tid]);
    __syncthreads();
#pragma unroll
    for (int k = 0; k < KK; k++) {
        int pos = lbase[ee[k]] + rk[k];
        perm[pos] = t;
        pgate[pos] = gates[t * KK + k];
        islot[t * KK + k] = pos;
    }
}

// ------------- bucketed expert chain: 32x32x16 bf16 MFMA (champion) -------
// r15 champion kernel, unchanged.
template <bool STG>
__global__ __launch_bounds__(256, 3) void k_expert(
    const ushort* __restrict__ xb, const ushort* __restrict__ kfb,
    const ushort* __restrict__ vfb,
    const int* __restrict__ perm, const float* __restrict__ pgate,
    const int* __restrict__ offsets, const int* __restrict__ counts,
    const int* __restrict__ tmape, const int* __restrict__ tmapt,
    const int* __restrict__ ntiles, ushort* __restrict__ stg,
    float* __restrict__ out)
{
    __shared__ __align__(1024) char xsb[2][64 * 256];
    __shared__ __align__(16) ushort hs[64][128];
    __shared__ float gl[64];
    __shared__ int tl[64];

    const int bid = (blockIdx.x & 7) * 132 + (blockIdx.x >> 3);
    if (bid >= ntiles[0]) return;
    const int e = tmape[bid];
    const int base = offsets[e] + tmapt[bid] * TILE;
    const int nr = min(TILE, offsets[e] + counts[e] - base);
    const int tid = threadIdx.x;

    if (tid < 64) {
        int tok = 0; float g = 0.f;
        if (tid < nr) { tok = perm[base + tid]; g = pgate[base + tid]; }
        tl[tid] = tok; gl[tid] = g;
    }
    __syncthreads();

    const int lane = tid & 63, wid = tid >> 6;
    const int wm = wid >> 1, wn = wid & 1;
    const int l31 = lane & 31, l5 = lane >> 5;

    const char* xbytes = (const char*)xb;
    const ushort* kb = kfb + ((size_t)e * 256 + wn * 2) * 512 + lane * 8;

    int srow[4]; const char* ssrc[4];
#pragma unroll
    for (int i = 0; i < 4; i++) {
        srow[i] = wid * 4096 + i * 1024;
        int row = wid * 16 + i * 4 + (lane >> 4);
        int colb = (lane & 15) * 16;
        ssrc[i] = xbytes + (size_t)tl[row] * 2048 + (colb ^ ((row & 15) << 4));
    }

    f32x16 acc0, acc1;
#pragma unroll
    for (int r = 0; r < 16; r++) { acc0[r] = 0.f; acc1[r] = 0.f; }

#pragma unroll
    for (int i = 0; i < 4; i++)
        gload_lds16(ssrc[i], xsb[0] + srow[i]);

    bf16x8 b0p[8], b1p[8];
#pragma unroll
    for (int j = 0; j < 8; j++) {
        b0p[j] = *(const bf16x8*)(kb + (size_t)j * 2048);
        b1p[j] = *(const bf16x8*)(kb + (size_t)j * 2048 + 512);
    }
    asm volatile("s_waitcnt vmcnt(16)" ::: "memory");
    __builtin_amdgcn_s_barrier();
    __builtin_amdgcn_sched_barrier(0);

    const int hr = wm * 32 + l31;
    const int asw = (hr & 15) << 4;

    for (int c = 0; c < 8; c++) {
        const int cur = c & 1;
        if (c < 7) {
#pragma unroll
            for (int i = 0; i < 4; i++)
                gload_lds16(ssrc[i] + (c + 1) * 256, xsb[cur ^ 1] + srow[i]);
        }
        const char* xcur = xsb[cur];
#pragma unroll
        for (int ksl = 0; ksl < 8; ksl++) {
            bf16x8 a = *(const bf16x8*)(xcur + hr * 256 + ((ksl * 32 + l5 * 16) ^ asw));
            int ks = c * 8 + ksl;
            acc0 = __builtin_amdgcn_mfma_f32_32x32x16_bf16(a, b0p[ksl], acc0, 0, 0, 0);
            acc1 = __builtin_amdgcn_mfma_f32_32x32x16_bf16(a, b1p[ksl], acc1, 0, 0, 0);
            int nk = (ks + 8) & 63;
            b0p[ksl] = *(const bf16x8*)(kb + (size_t)nk * 2048);
            b1p[ksl] = *(const bf16x8*)(kb + (size_t)nk * 2048 + 512);
        }
        asm volatile("s_waitcnt vmcnt(16)" ::: "memory");
        __builtin_amdgcn_s_barrier();
        __builtin_amdgcn_sched_barrier(0);
    }

#pragma unroll
    for (int r = 0; r < 16; r++) {
        int row = (r & 3) + 8 * (r >> 2) + 4 * l5;
        int grow = wm * 32 + row;
        float g = gl[grow];
        int c0 = wn * 64 + l31;
        int c1 = c0 + 32;
        int sw = (grow & 7) << 3;
        hs[grow][c0 ^ sw] = f2b(fmaxf(acc0[r], 0.f) * g);
        hs[grow][c1 ^ sw] = f2b(fmaxf(acc1[r], 0.f) * g);
    }
    __syncthreads();

    bf16x8 af[8];
    const int hsw = (hr & 7) << 3;
#pragma unroll
    for (int ks = 0; ks < 8; ks++) {
        int cc = ks * 16 + l5 * 8;
        af[ks] = *(const bf16x8*)&hs[hr][cc ^ hsw];
    }

    const ushort* vb = vfb + ((size_t)e * 32 + wn * 16) * 4096 + lane * 8;
    bf16x8 vpa[4], vpb[4];
#pragma unroll
    for (int j = 0; j < 4; j++) {
        vpa[j] = *(const bf16x8*)(vb + (size_t)j * 512);
        vpb[j] = *(const bf16x8*)(vb + (size_t)(4 + j) * 512);
    }

#pragma unroll
    for (int nv = 0; nv < 16; nv++) {
        f32x16 acc;
#pragma unroll
        for (int r = 0; r < 16; r++) acc[r] = 0.f;
#pragma unroll
        for (int ks = 0; ks < 4; ks++)
            acc = __builtin_amdgcn_mfma_f32_32x32x16_bf16(af[ks], vpa[ks], acc, 0, 0, 0);
        if (nv < 15) {
#pragma unroll
            for (int j = 0; j < 4; j++)
                vpa[j] = *(const bf16x8*)(vb + ((size_t)(nv + 1) * 8 + j) * 512);
        }
#pragma unroll
        for (int ks = 0; ks < 4; ks++)
            acc = __builtin_amdgcn_mfma_f32_32x32x16_bf16(af[4 + ks], vpb[ks], acc, 0, 0, 0);
        if (nv < 15) {
#pragma unroll
            for (int j = 0; j < 4; j++)
                vpb[j] = *(const bf16x8*)(vb + ((size_t)(nv + 1) * 8 + 4 + j) * 512);
        }
        const int colb = wn * 512 + nv * 32 + l31;
#pragma unroll
        for (int r = 0; r < 16; r++) {
            int row = wm * 32 + (r & 3) + 8 * (r >> 2) + 4 * l5;
            if (row < nr) {
                if (STG)
                    stg[(size_t)(base + row) * VV + colb] = f2b(acc[r]);
                else
                    atomicAdd(&out[(size_t)tl[row] * VV + colb], acc[r]);
            }
        }
    }
}

// ------------- combine: out[t] = sum_k stg[islot[t][k]]  (streaming) ------
__global__ __launch_bounds__(256) void k_combine(const ushort* __restrict__ stg,
                                                 const int* __restrict__ islot,
                                                 float* __restrict__ out) {
    const int tid = threadIdx.x;
    const int t = blockIdx.x * 2 + (tid >> 7);
    const int c8 = (tid & 127) * 8;
    const int4 sl = *(const int4*)&islot[t * KK];
    float acc[8];
#pragma unroll
    for (int j = 0; j < 8; j++) acc[j] = 0.f;
    const int slots[4] = { sl.x, sl.y, sl.z, sl.w };
#pragma unroll
    for (int k = 0; k < KK; k++) {
        bf16x8 v = *(const bf16x8*)(stg + (size_t)slots[k] * VV + c8);
#pragma unroll
        for (int j = 0; j < 8; j++) acc[j] += b2f((ushort)v[j]);
    }
    float4 o0 = { acc[0], acc[1], acc[2], acc[3] };
    float4 o1 = { acc[4], acc[5], acc[6], acc[7] };
    *(float4*)&out[(size_t)t * VV + c8] = o0;
    *(float4*)&out[(size_t)t * VV + c8 + 4] = o1;
}

// --------------------------------------------------------------------------
extern "C" void kernel_launch(void* const* d_in, const int* in_sizes, int n_in,
                              void* d_out, int out_size, void* d_ws, size_t ws_size,
                              hipStream_t stream) {
    const float* x      = (const float*)d_in[0];
    const float* keys   = (const float*)d_in[1];
    const float* values = (const float*)d_in[2];
    const float* esel   = (const float*)d_in[3];
    float* out = (float*)d_out;

    float* wsf = (float*)d_ws;
    int*   wsi = (int*)d_ws;

    float* gates   = wsf + WS_GATES;
    float* pgate   = wsf + WS_PGATE;
    float* lm_sums = wsf + WS_LMSUMS;
    int*   counts  = wsi + WS_COUNTS;
    int*   offsets = wsi + WS_OFFSETS;
    int*   cursors = wsi + WS_CURSORS;
    int*   ntiles  = wsi + WS_NTILES;
    int*   tmape   = wsi + WS_TMAPE;
    int*   tmapt   = wsi + WS_TMAPT;
    int*   idxs    = wsi + WS_IDXS;
    int*   perm    = wsi + WS_PERM;
    int*   islot   = wsi + WS_ISLOT;
    uint*   xbu = (uint*)(wsf + WS_XB);
    ushort* xb  = (ushort*)xbu;
    ushort* kfb = (ushort*)(wsf + WS_KF);
    ushort* vfb = (ushort*)(wsf + WS_VF);
    ushort* stg = (ushort*)(wsf + WS_STG);

    const bool use_stg = ws_size >= WS_NEED_U * 4ull;
    float* sel_part = use_stg ? (float*)stg : (float*)kfb;

    if (!use_stg)
        hipMemsetAsync(d_out, 0, (size_t)TT * VV * sizeof(float), stream);

    k_router<<<dim3(TT / 64, RSPLIT), 128, 0, stream>>>(x, esel, sel_part, xbu,
                                                        wsf + WS_STATS);
    k_token<<<TT / 256, 256, 0, stream>>>(sel_part, gates, idxs, lm_sums, counts);

    k_prep<<<EE * 64 + EE * 64, 256, 0, stream>>>(keys, values, kfb, vfb);

    k_scan<<<1, 64, 0, stream>>>(counts, offsets, cursors, tmape, tmapt, ntiles,
                                 lm_sums, out + (size_t)TT * VV);
    k_scatter<<<TT / 256, 256, 0, stream>>>(idxs, gates, cursors, perm, pgate, islot);
    if (use_stg) {
        k_expert<true><<<NTILE_MAX, 256, 0, stream>>>(xb, kfb, vfb, perm, pgate,
                                                      offsets, counts, tmape, tmapt,
                                                      ntiles, stg, out);
        k_combine<<<TT / 2, 256, 0, stream>>>(stg, islot, out);
    } else {
        k_expert<false><<<NTILE_MAX, 256, 0, stream>>>(xb, kfb, vfb, perm, pgate,
                                                       offsets, counts, tmape, tmapt,
                                                       ntiles, stg, out);
    }
}

// Round 19
// 193.794 us; speedup vs baseline: 1.2527x; 1.2527x over previous
//
#include <hip/hip_runtime.h>

typedef unsigned int uint;
typedef unsigned short ushort;

#define TT 16384      // tokens = B*S
#define DD 1024       // d_model
#define EE 32         // experts
#define ESS 128       // expert size
#define VV 1024       // v dim
#define KK 4          // top-k
#define TILE 64
#define NTILE_MAX 1056   // 16384*4/64 + 32 ; == 8*132 (XCD-swizzle friendly)
#define RSPLIT 8         // router D-split

typedef __attribute__((ext_vector_type(8))) short bf16x8;   // 8 bf16 = 4 VGPR
typedef __attribute__((ext_vector_type(16))) float f32x16;

// ---------------- ws layout (offsets in 4B units) ----------------
#define WS_SELRAW   0                       // 524288 f (unused, layout stability)
#define WS_GATES    524288                  // 65536 f
#define WS_PGATE    589824                  // 65536 f
#define WS_STATS    655360                  // lm_sums 32 f + counts 32 i (zeroed by k_router blk0)
#define WS_LMSUMS   655360
#define WS_COUNTS   655392
#define WS_OFFSETS  655424                  // 33 i
#define WS_CURSORS  655457                  // 32 i
#define WS_NTILES   655489                  // 1 i
#define WS_TMAPE    655490                  // 1056 i
#define WS_TMAPT    656546                  // 1056 i
#define WS_IDXS     657602                  // 65536 i
#define WS_PERM     723138                  // 65536 i
// bf16 buffers (16B-aligned starts, sizes in uint units)
#define WS_XB       788736                  // x bf16 [16384][1024] -> 8388608 uints
#define WS_KF       9177344                 // keys frag-major [32][64][4][64][8] -> 2097152 uints
#define WS_VF       11274496                // values frag-major [32][32][8][64][8] -> 2097152 uints
#define WS_ISLOT    13371648                // token -> 4 slot ids, 65536 i
#define WS_STG      13437184                // slot partials bf16 [65536][1024] -> 33554432 uints
#define WS_NEED_U   46991616ull             // uints needed for staging path
// router partials [RSPLIT][TT][EE] f32 alias onto WS_STG (written later by
// k_expert) or, in the fallback, onto WS_KF..WS_VF (written later by k_prep,
// which therefore launches AFTER k_token).

// fp32 -> bf16 RNE
__device__ __forceinline__ ushort f2b(float f) {
    uint u = __builtin_bit_cast(uint, f);
    u = (u + 0x7fffu + ((u >> 16) & 1u)) >> 16;
    return (ushort)u;
}
__device__ __forceinline__ uint bpack(float lo, float hi) {
    return (uint)f2b(lo) | ((uint)f2b(hi) << 16);
}
__device__ __forceinline__ float b2f(ushort b) {
    uint u = (uint)b << 16;
    return __builtin_bit_cast(float, u);
}

// async global->LDS, 16B per lane; LDS dest = wave-uniform base + lane*16,
// global src is per-lane (m104/m173 semantics)
__device__ __forceinline__ void gload_lds16(const void* g, void* l) {
    __builtin_amdgcn_global_load_lds(
        (const __attribute__((address_space(1))) uint*)g,
        (__attribute__((address_space(3))) uint*)l, 16, 0, 0);
}

// ------------- fused weight prep: keys + values -> B-fragment-major bf16 ---
__global__ __launch_bounds__(256) void k_prep(const float* __restrict__ keys,
                                              const float* __restrict__ values,
                                              ushort* __restrict__ kfb,
                                              ushort* __restrict__ vfb) {
    const int l = threadIdx.x & 63;
    int b = blockIdx.x;
    if (b < EE * 64) {
        const int e = b >> 6, ks = b & 63;
        const int nf = threadIdx.x >> 6;
        const int f = nf * 32 + (l & 31);
        const int d0 = ks * 16 + (l >> 5) * 8;
        const float* src = keys + ((size_t)e * DD + d0) * ESS + f;
        float v[8];
#pragma unroll
        for (int j = 0; j < 8; j++) v[j] = src[(size_t)j * ESS];
        uint4 r = { bpack(v[0], v[1]), bpack(v[2], v[3]), bpack(v[4], v[5]), bpack(v[6], v[7]) };
        const size_t off = (((size_t)e * 64 + ks) * 4 + nf) * 512 + l * 8;
        *(uint4*)(kfb + off) = r;
    } else {
        b -= EE * 64;
        const int half = b & 1;
        const int env = b >> 1;
        const int e = env >> 5, nv = env & 31;
        const int ks = (threadIdx.x >> 6) + half * 4;
        const int v0 = nv * 32 + (l & 31);
        const int f0 = ks * 16 + (l >> 5) * 8;
        const float* src = values + ((size_t)e * ESS + f0) * VV + v0;
        float v[8];
#pragma unroll
        for (int j = 0; j < 8; j++) v[j] = src[(size_t)j * VV];
        uint4 r = { bpack(v[0], v[1]), bpack(v[2], v[3]), bpack(v[4], v[5]), bpack(v[6], v[7]) };
        const size_t off = (((size_t)e * 32 + nv) * 8 + ks) * 512 + l * 8;
        *(uint4*)(vfb + off) = r;
    }
}

// ------------- router: sel_part[c] = X * Wsel^T over D-chunk c (fp32!) ----
// fp32 on purpose: bf16 logits flip ~1% of top-4 picks -> O(1) output errors.
// Block (0,0) zeroes the stats region (safe: k_token runs after, stream order).
// r17-champion mapping: 2 experts x 4 tokens per thread, 256-thread blocks.
// This layout is LDS-bank-conflict-free BY CONSTRUCTION (ss rows at 136-float
// offsets -> distinct banks within each 16-lane group; xs tg-groups at
// 272-float offsets -> distinct banks). r18's 2x8/128-thread remap broke both
// (1.05M conflicts, VGPR 184, occupancy 10.7% -> router 100us). Do not touch.
__global__ __launch_bounds__(256) void k_router(const float* __restrict__ x,
                                                const float* __restrict__ sel,
                                                float* __restrict__ sel_part,
                                                uint* __restrict__ xbu,
                                                float* __restrict__ stats) {
    __shared__ float xs[64][68];
    __shared__ float ss[32][68];
    const int tid = threadIdx.x;
    if (blockIdx.x == 0 && blockIdx.y == 0 && tid < 64) stats[tid] = 0.f;
    const int t0 = blockIdx.x * 64;
    const int dch = blockIdx.y;                 // D-chunk 0..RSPLIT-1
    const int eg = tid & 15;                    // expert pair: 2eg, 2eg+1
    const int tg = tid >> 4;                    // token group: tg*4..+3
    float acc0[4], acc1[4];
#pragma unroll
    for (int i = 0; i < 4; i++) { acc0[i] = 0.f; acc1[i] = 0.f; }

    const int dlen = DD / RSPLIT;               // 128
    for (int dc = dch * dlen; dc < dch * dlen + dlen; dc += 64) {
#pragma unroll
        for (int i = 0; i < 4; i++) {
            int q = tid + 256 * i;
            int r = q >> 4, c4 = q & 15;
            size_t gi = (size_t)(t0 + r) * DD + dc + c4 * 4;
            float4 v = *(const float4*)&x[gi];
            *(float4*)&xs[r][c4 * 4] = v;
            uint2 bv = { bpack(v.x, v.y), bpack(v.z, v.w) };   // fused bf16 emit
            *(uint2*)&xbu[gi / 2] = bv;
        }
#pragma unroll
        for (int i = 0; i < 2; i++) {
            int q = tid + 256 * i;
            int e = q >> 4, c4 = q & 15;
            float4 v = *(const float4*)&sel[(size_t)e * DD + dc + c4 * 4];
            *(float4*)&ss[e][c4 * 4] = v;
        }
        __syncthreads();
#pragma unroll
        for (int d4 = 0; d4 < 16; d4++) {
            float4 sv0 = *(const float4*)&ss[2 * eg][d4 * 4];
            float4 sv1 = *(const float4*)&ss[2 * eg + 1][d4 * 4];
#pragma unroll
            for (int i = 0; i < 4; i++) {
                float4 xv = *(const float4*)&xs[tg * 4 + i][d4 * 4];
                acc0[i] += xv.x * sv0.x + xv.y * sv0.y + xv.z * sv0.z + xv.w * sv0.w;
                acc1[i] += xv.x * sv1.x + xv.y * sv1.y + xv.z * sv1.z + xv.w * sv1.w;
            }
        }
        __syncthreads();
    }
    float* dst = sel_part + (size_t)dch * TT * EE;
#pragma unroll
    for (int i = 0; i < 4; i++) {
        float2 o = { acc0[i], acc1[i] };
        *(float2*)&dst[(size_t)(t0 + tg * 4 + i) * EE + 2 * eg] = o;
    }
}

// ------------- per-token: sum partials, lse, sigmoid, top-4 ---------------
__global__ __launch_bounds__(256) void k_token(const float* __restrict__ sel_part,
                                               float* __restrict__ gates,
                                               int* __restrict__ idxs,
                                               float* __restrict__ lm_sums,
                                               int* __restrict__ counts) {
    __shared__ int hist[EE];
    __shared__ float lmh[EE];
    const int tid = threadIdx.x;
    if (tid < EE) { hist[tid] = 0; lmh[tid] = 0.f; }
    __syncthreads();

    const int t = blockIdx.x * 256 + tid;
    float v[32];
#pragma unroll
    for (int j = 0; j < 8; j++) {
        float4 q[RSPLIT];
#pragma unroll
        for (int p = 0; p < RSPLIT; p++)
            q[p] = *(const float4*)&sel_part[((size_t)p * TT + t) * EE + j * 4];
        v[j * 4 + 0] = ((q[0].x + q[1].x) + (q[2].x + q[3].x)) + ((q[4].x + q[5].x) + (q[6].x + q[7].x));
        v[j * 4 + 1] = ((q[0].y + q[1].y) + (q[2].y + q[3].y)) + ((q[4].y + q[5].y) + (q[6].y + q[7].y));
        v[j * 4 + 2] = ((q[0].z + q[1].z) + (q[2].z + q[3].z)) + ((q[4].z + q[5].z) + (q[6].z + q[7].z));
        v[j * 4 + 3] = ((q[0].w + q[1].w) + (q[2].w + q[3].w)) + ((q[4].w + q[5].w) + (q[6].w + q[7].w));
    }
    float m = v[0];
#pragma unroll
    for (int e = 1; e < 32; e++) m = fmaxf(m, v[e]);
    float s = 0.f;
#pragma unroll
    for (int e = 0; e < 32; e++) s += expf(v[e] - m);
    const float lse = logf(s) + m;

    float sg[32];
#pragma unroll
    for (int e = 0; e < 32; e++) sg[e] = 1.f / (1.f + expf(-v[e]));

    unsigned taken = 0u;
#pragma unroll
    for (int k = 0; k < KK; k++) {
        float best = -1.f; int bi = 0;
#pragma unroll
        for (int e = 0; e < 32; e++) {
            bool free_e = !((taken >> e) & 1u);
            if (free_e && sg[e] > best) { best = sg[e]; bi = e; }
        }
        taken |= 1u << bi;
        gates[t * KK + k] = best;
        idxs[t * KK + k] = bi;
        atomicAdd(&hist[bi], 1);
    }

#pragma unroll
    for (int e = 0; e < 32; e++) {
        float pv = expf(v[e] - lse);
#pragma unroll
        for (int o = 32; o >= 1; o >>= 1) pv += __shfl_xor(pv, o, 64);
        if ((tid & 63) == 0) atomicAdd(&lmh[e], pv);
    }
    __syncthreads();
    if (tid < EE) {
        atomicAdd(&counts[tid], hist[tid]);
        atomicAdd(&lm_sums[tid], lmh[tid]);
    }
}

// ------------- wave-parallel: scan counts, tile map, reg_loss -------------
__global__ void k_scan(const int* __restrict__ counts, int* __restrict__ offsets,
                       int* __restrict__ cursors, int* __restrict__ tmape,
                       int* __restrict__ tmapt, int* __restrict__ ntiles,
                       const float* __restrict__ lm_sums, float* __restrict__ out_reg) {
    const int lane = threadIdx.x;          // one wave of 64
    int c = (lane < EE) ? counts[lane] : 0;
    int p = c;
#pragma unroll
    for (int o = 1; o < 32; o <<= 1) { int u = __shfl_up(p, o, 64); if (lane >= o) p += u; }
    const int off = p - c;
    if (lane < EE) { offsets[lane] = off; cursors[lane] = off; }
    if (lane == EE - 1) offsets[EE] = p;

    int nt = (c + TILE - 1) / TILE;
    int q = nt;
#pragma unroll
    for (int o = 1; o < 32; o <<= 1) { int u = __shfl_up(q, o, 64); if (lane >= o) q += u; }
    const int tb = q - nt;
    if (lane < EE)
        for (int j = 0; j < nt; j++) { tmape[tb + j] = lane; tmapt[tb + j] = j; }
    if (lane == EE - 1) ntiles[0] = q;

    float rv = 0.f;
    if (lane < EE) {
        float pe = lm_sums[lane] * (1.f / (float)TT);
        rv = pe * logf(pe);
    }
#pragma unroll
    for (int o = 16; o >= 1; o >>= 1) rv += __shfl_down(rv, o, 64);
    if (lane == 0) out_reg[0] = rv;
}

// ------------- scatter token ids into per-expert buckets (block-agg) ------
__global__ __launch_bounds__(256) void k_scatter(const int* __restrict__ idxs,
                                                 const float* __restrict__ gates,
                                                 int* __restrict__ cursors,
                                                 int* __restrict__ perm,
                                                 float* __restrict__ pgate,
                                                 int* __restrict__ islot) {
    __shared__ int lh[EE];
    __shared__ int lbase[EE];
    const int tid = threadIdx.x;
    if (tid < EE) lh[tid] = 0;
    __syncthreads();
    const int t = blockIdx.x * 256 + tid;
    int ee[KK], rk[KK];
#pragma unroll
    for (int k = 0; k < KK; k++) {
        ee[k] = idxs[t * KK + k];
        rk[k] = atomicAdd(&lh[ee[k]], 1);
    }
    __syncthreads();
    if (tid < EE) lbase[tid] = atomicAdd(&cursors[tid], lh[tid]);
    __syncthreads();
#pragma unroll
    for (int k = 0; k < KK; k++) {
        int pos = lbase[ee[k]] + rk[k];
        perm[pos] = t;
        pgate[pos] = gates[t * KK + k];
        islot[t * KK + k] = pos;
    }
}

// ------------- bucketed expert chain: 32x32x16 bf16 MFMA (champion) -------
// r15 champion kernel, unchanged (8 perturbations all null/negative).
template <bool STG>
__global__ __launch_bounds__(256, 3) void k_expert(
    const ushort* __restrict__ xb, const ushort* __restrict__ kfb,
    const ushort* __restrict__ vfb,
    const int* __restrict__ perm, const float* __restrict__ pgate,
    const int* __restrict__ offsets, const int* __restrict__ counts,
    const int* __restrict__ tmape, const int* __restrict__ tmapt,
    const int* __restrict__ ntiles, ushort* __restrict__ stg,
    float* __restrict__ out)
{
    __shared__ __align__(1024) char xsb[2][64 * 256];
    __shared__ __align__(16) ushort hs[64][128];
    __shared__ float gl[64];
    __shared__ int tl[64];

    const int bid = (blockIdx.x & 7) * 132 + (blockIdx.x >> 3);
    if (bid >= ntiles[0]) return;
    const int e = tmape[bid];
    const int base = offsets[e] + tmapt[bid] * TILE;
    const int nr = min(TILE, offsets[e] + counts[e] - base);
    const int tid = threadIdx.x;

    if (tid < 64) {
        int tok = 0; float g = 0.f;
        if (tid < nr) { tok = perm[base + tid]; g = pgate[base + tid]; }
        tl[tid] = tok; gl[tid] = g;
    }
    __syncthreads();

    const int lane = tid & 63, wid = tid >> 6;
    const int wm = wid >> 1, wn = wid & 1;
    const int l31 = lane & 31, l5 = lane >> 5;

    const char* xbytes = (const char*)xb;
    const ushort* kb = kfb + ((size_t)e * 256 + wn * 2) * 512 + lane * 8;

    int srow[4]; const char* ssrc[4];
#pragma unroll
    for (int i = 0; i < 4; i++) {
        srow[i] = wid * 4096 + i * 1024;
        int row = wid * 16 + i * 4 + (lane >> 4);
        int colb = (lane & 15) * 16;
        ssrc[i] = xbytes + (size_t)tl[row] * 2048 + (colb ^ ((row & 15) << 4));
    }

    f32x16 acc0, acc1;
#pragma unroll
    for (int r = 0; r < 16; r++) { acc0[r] = 0.f; acc1[r] = 0.f; }

#pragma unroll
    for (int i = 0; i < 4; i++)
        gload_lds16(ssrc[i], xsb[0] + srow[i]);

    bf16x8 b0p[8], b1p[8];
#pragma unroll
    for (int j = 0; j < 8; j++) {
        b0p[j] = *(const bf16x8*)(kb + (size_t)j * 2048);
        b1p[j] = *(const bf16x8*)(kb + (size_t)j * 2048 + 512);
    }
    asm volatile("s_waitcnt vmcnt(16)" ::: "memory");
    __builtin_amdgcn_s_barrier();
    __builtin_amdgcn_sched_barrier(0);

    const int hr = wm * 32 + l31;
    const int asw = (hr & 15) << 4;

    for (int c = 0; c < 8; c++) {
        const int cur = c & 1;
        if (c < 7) {
#pragma unroll
            for (int i = 0; i < 4; i++)
                gload_lds16(ssrc[i] + (c + 1) * 256, xsb[cur ^ 1] + srow[i]);
        }
        const char* xcur = xsb[cur];
#pragma unroll
        for (int ksl = 0; ksl < 8; ksl++) {
            bf16x8 a = *(const bf16x8*)(xcur + hr * 256 + ((ksl * 32 + l5 * 16) ^ asw));
            int ks = c * 8 + ksl;
            acc0 = __builtin_amdgcn_mfma_f32_32x32x16_bf16(a, b0p[ksl], acc0, 0, 0, 0);
            acc1 = __builtin_amdgcn_mfma_f32_32x32x16_bf16(a, b1p[ksl], acc1, 0, 0, 0);
            int nk = (ks + 8) & 63;
            b0p[ksl] = *(const bf16x8*)(kb + (size_t)nk * 2048);
            b1p[ksl] = *(const bf16x8*)(kb + (size_t)nk * 2048 + 512);
        }
        asm volatile("s_waitcnt vmcnt(16)" ::: "memory");
        __builtin_amdgcn_s_barrier();
        __builtin_amdgcn_sched_barrier(0);
    }

#pragma unroll
    for (int r = 0; r < 16; r++) {
        int row = (r & 3) + 8 * (r >> 2) + 4 * l5;
        int grow = wm * 32 + row;
        float g = gl[grow];
        int c0 = wn * 64 + l31;
        int c1 = c0 + 32;
        int sw = (grow & 7) << 3;
        hs[grow][c0 ^ sw] = f2b(fmaxf(acc0[r], 0.f) * g);
        hs[grow][c1 ^ sw] = f2b(fmaxf(acc1[r], 0.f) * g);
    }
    __syncthreads();

    bf16x8 af[8];
    const int hsw = (hr & 7) << 3;
#pragma unroll
    for (int ks = 0; ks < 8; ks++) {
        int cc = ks * 16 + l5 * 8;
        af[ks] = *(const bf16x8*)&hs[hr][cc ^ hsw];
    }

    const ushort* vb = vfb + ((size_t)e * 32 + wn * 16) * 4096 + lane * 8;
    bf16x8 vpa[4], vpb[4];
#pragma unroll
    for (int j = 0; j < 4; j++) {
        vpa[j] = *(const bf16x8*)(vb + (size_t)j * 512);
        vpb[j] = *(const bf16x8*)(vb + (size_t)(4 + j) * 512);
    }

#pragma unroll
    for (int nv = 0; nv < 16; nv++) {
        f32x16 acc;
#pragma unroll
        for (int r = 0; r < 16; r++) acc[r] = 0.f;
#pragma unroll
        for (int ks = 0; ks < 4; ks++)
            acc = __builtin_amdgcn_mfma_f32_32x32x16_bf16(af[ks], vpa[ks], acc, 0, 0, 0);
        if (nv < 15) {
#pragma unroll
            for (int j = 0; j < 4; j++)
                vpa[j] = *(const bf16x8*)(vb + ((size_t)(nv + 1) * 8 + j) * 512);
        }
#pragma unroll
        for (int ks = 0; ks < 4; ks++)
            acc = __builtin_amdgcn_mfma_f32_32x32x16_bf16(af[4 + ks], vpb[ks], acc, 0, 0, 0);
        if (nv < 15) {
#pragma unroll
            for (int j = 0; j < 4; j++)
                vpb[j] = *(const bf16x8*)(vb + ((size_t)(nv + 1) * 8 + 4 + j) * 512);
        }
        const int colb = wn * 512 + nv * 32 + l31;
#pragma unroll
        for (int r = 0; r < 16; r++) {
            int row = wm * 32 + (r & 3) + 8 * (r >> 2) + 4 * l5;
            if (row < nr) {
                if (STG)
                    stg[(size_t)(base + row) * VV + colb] = f2b(acc[r]);
                else
                    atomicAdd(&out[(size_t)tl[row] * VV + colb], acc[r]);
            }
        }
    }
}

// ------------- combine: out[t] = sum_k stg[islot[t][k]]  (streaming) ------
__global__ __launch_bounds__(256) void k_combine(const ushort* __restrict__ stg,
                                                 const int* __restrict__ islot,
                                                 float* __restrict__ out) {
    const int tid = threadIdx.x;
    const int t = blockIdx.x * 2 + (tid >> 7);
    const int c8 = (tid & 127) * 8;
    const int4 sl = *(const int4*)&islot[t * KK];
    float acc[8];
#pragma unroll
    for (int j = 0; j < 8; j++) acc[j] = 0.f;
    const int slots[4] = { sl.x, sl.y, sl.z, sl.w };
#pragma unroll
    for (int k = 0; k < KK; k++) {
        bf16x8 v = *(const bf16x8*)(stg + (size_t)slots[k] * VV + c8);
#pragma unroll
        for (int j = 0; j < 8; j++) acc[j] += b2f((ushort)v[j]);
    }
    float4 o0 = { acc[0], acc[1], acc[2], acc[3] };
    float4 o1 = { acc[4], acc[5], acc[6], acc[7] };
    *(float4*)&out[(size_t)t * VV + c8] = o0;
    *(float4*)&out[(size_t)t * VV + c8 + 4] = o1;
}

// --------------------------------------------------------------------------
extern "C" void kernel_launch(void* const* d_in, const int* in_sizes, int n_in,
                              void* d_out, int out_size, void* d_ws, size_t ws_size,
                              hipStream_t stream) {
    const float* x      = (const float*)d_in[0];
    const float* keys   = (const float*)d_in[1];
    const float* values = (const float*)d_in[2];
    const float* esel   = (const float*)d_in[3];
    float* out = (float*)d_out;

    float* wsf = (float*)d_ws;
    int*   wsi = (int*)d_ws;

    float* gates   = wsf + WS_GATES;
    float* pgate   = wsf + WS_PGATE;
    float* lm_sums = wsf + WS_LMSUMS;
    int*   counts  = wsi + WS_COUNTS;
    int*   offsets = wsi + WS_OFFSETS;
    int*   cursors = wsi + WS_CURSORS;
    int*   ntiles  = wsi + WS_NTILES;
    int*   tmape   = wsi + WS_TMAPE;
    int*   tmapt   = wsi + WS_TMAPT;
    int*   idxs    = wsi + WS_IDXS;
    int*   perm    = wsi + WS_PERM;
    int*   islot   = wsi + WS_ISLOT;
    uint*   xbu = (uint*)(wsf + WS_XB);
    ushort* xb  = (ushort*)xbu;
    ushort* kfb = (ushort*)(wsf + WS_KF);
    ushort* vfb = (ushort*)(wsf + WS_VF);
    ushort* stg = (ushort*)(wsf + WS_STG);

    const bool use_stg = ws_size >= WS_NEED_U * 4ull;
    float* sel_part = use_stg ? (float*)stg : (float*)kfb;

    if (!use_stg)
        hipMemsetAsync(d_out, 0, (size_t)TT * VV * sizeof(float), stream);

    k_router<<<dim3(TT / 64, RSPLIT), 256, 0, stream>>>(x, esel, sel_part, xbu,
                                                        wsf + WS_STATS);
    k_token<<<TT / 256, 256, 0, stream>>>(sel_part, gates, idxs, lm_sums, counts);

    k_prep<<<EE * 64 + EE * 64, 256, 0, stream>>>(keys, values, kfb, vfb);

    k_scan<<<1, 64, 0, stream>>>(counts, offsets, cursors, tmape, tmapt, ntiles,
                                 lm_sums, out + (size_t)TT * VV);
    k_scatter<<<TT / 256, 256, 0, stream>>>(idxs, gates, cursors, perm, pgate, islot);
    if (use_stg) {
        k_expert<true><<<NTILE_MAX, 256, 0, stream>>>(xb, kfb, vfb, perm, pgate,
                                                      offsets, counts, tmape, tmapt,
                                                      ntiles, stg, out);
        k_combine<<<TT / 2, 256, 0, stream>>>(stg, islot, out);
    } else {
        k_expert<false><<<NTILE_MAX, 256, 0, stream>>>(xb, kfb, vfb, perm, pgate,
                                                       offsets, counts, tmape, tmapt,
                                                       ntiles, stg, out);
    }
}